// Round 1
// baseline (13921.538 us; speedup 1.0000x reference)
//
#include <hip/hip_runtime.h>
#include <math.h>

#define NB   32      // blocks
#define NTH  256     // threads per block
#define CH   64      // neurons per block (N/NB)
#define NN   2048    // N
#define DD   64      // D
#define TT   512     // T
#define KWTA 256

// Cross-block communication buffers (ping-pong on step parity).
__device__ __align__(16) double g_L1[2][NB];
__device__ __align__(16) double g_r [2][NB][DD];
__device__ __align__(16) double g_s [2][NB];
__device__ __align__(16) double g_e [2][NB][DD];
__device__ __align__(16) float  g_xg[2][NN];
__device__ __align__(16) float  g_yg[2][NN];
__device__ unsigned g_bar;

__global__ void bdh_init() { if (threadIdx.x == 0) g_bar = 0u; }

__device__ __forceinline__ void grid_barrier(unsigned& epoch) {
  __syncthreads();
  if (threadIdx.x == 0) {
    epoch += 1u;
    __threadfence();  // release all block writes device-wide
    __hip_atomic_fetch_add(&g_bar, 1u, __ATOMIC_ACQ_REL, __HIP_MEMORY_SCOPE_AGENT);
    const unsigned target = epoch * (unsigned)NB;
    while (__hip_atomic_load(&g_bar, __ATOMIC_ACQUIRE, __HIP_MEMORY_SCOPE_AGENT) < target)
      __builtin_amdgcn_s_sleep(1);
  }
  __syncthreads();
}

__device__ __forceinline__ float dot16(const float* __restrict__ g, const float* __restrict__ v) {
  const float4* q = (const float4*)g;
  float4 a = q[0], b = q[1], c = q[2], d = q[3];
  float s = a.x*v[0] + a.y*v[1] + a.z*v[2] + a.w*v[3];
  s += b.x*v[4] + b.y*v[5] + b.z*v[6] + b.w*v[7];
  s += c.x*v[8] + c.y*v[9] + c.z*v[10] + c.w*v[11];
  s += d.x*v[12] + d.y*v[13] + d.z*v[14] + d.w*v[15];
  return s;
}

// Exact top-K threshold + stable (lowest-index-first) tie mask over 2048
// nonnegative floats in gv. Fills keep[0..CH) for global indices [n0,n0+CH).
// Radix select on float bit patterns (nonneg floats order like uints).
__device__ void select_topk(const float* __restrict__ gv, int K, int n0, int tid,
                            float* __restrict__ keep,
                            unsigned* __restrict__ hist,   // LDS [4*256]
                            unsigned* __restrict__ wsum,   // LDS [8]
                            int* __restrict__ misc)        // LDS [4]
{
  const int wave = tid >> 6, lane = tid & 63;
  unsigned keys[8];
  {
    const float4* p = ((const float4*)gv) + tid*2;
    float4 v0 = p[0], v1 = p[1];
    keys[0]=__float_as_uint(v0.x); keys[1]=__float_as_uint(v0.y);
    keys[2]=__float_as_uint(v0.z); keys[3]=__float_as_uint(v0.w);
    keys[4]=__float_as_uint(v1.x); keys[5]=__float_as_uint(v1.y);
    keys[6]=__float_as_uint(v1.z); keys[7]=__float_as_uint(v1.w);
  }
  unsigned prefix = 0u, pmask = 0u;
  int remK = K;
  for (int lev = 0; lev < 4; ++lev) {
    const int shf = 24 - 8*lev;
    #pragma unroll
    for (int j = 0; j < 4; ++j) hist[tid + 256*j] = 0u;
    __syncthreads();
    unsigned* h = hist + 256*wave;   // per-wave hist to cut atomic contention
    #pragma unroll
    for (int j = 0; j < 8; ++j)
      if ((keys[j] & pmask) == prefix)
        atomicAdd(&h[(keys[j] >> shf) & 255u], 1u);
    __syncthreads();
    const unsigned c = hist[tid] + hist[256+tid] + hist[512+tid] + hist[768+tid];
    unsigned s = c;  // inclusive suffix sum over bucket index (= tid)
    #pragma unroll
    for (int off = 1; off < 64; off <<= 1) {
      unsigned o = __shfl_down(s, off, 64);
      if (lane + off < 64) s += o;
    }
    if (lane == 0) wsum[wave] = s;
    __syncthreads();
    unsigned hi = 0;
    for (int w = wave + 1; w < 4; ++w) hi += wsum[w];
    const unsigned A = s + hi;       // count of keys with bucket >= tid
    if (A >= (unsigned)remK && (A - c) < (unsigned)remK) {  // unique crossing
      misc[0] = tid;
      misc[1] = remK - (int)(A - c);
    }
    __syncthreads();
    prefix |= ((unsigned)misc[0]) << shf;
    pmask  |= (255u << shf);
    remK = misc[1];
    __syncthreads();
  }
  const unsigned thr = prefix;
  const unsigned R = (unsigned)remK;   // # of thr-equal entries kept (lowest idx first)
  int lc[8]; int cnt = 0;
  #pragma unroll
  for (int j = 0; j < 8; ++j) { lc[j] = cnt; cnt += (keys[j] == thr) ? 1 : 0; }
  unsigned e = (unsigned)cnt;          // stable rank among equals: prefix over index
  #pragma unroll
  for (int off = 1; off < 64; off <<= 1) {
    unsigned o = __shfl_up(e, off, 64);
    if (lane >= off) e += o;
  }
  if (lane == 63) wsum[4 + wave] = e;
  __syncthreads();
  unsigned base = 0;
  for (int w = 0; w < wave; ++w) base += wsum[4 + w];
  const unsigned excl = base + e - (unsigned)cnt;
  #pragma unroll
  for (int j = 0; j < 8; ++j) {
    const int g = tid*8 + j;
    const unsigned gg = (unsigned)(g - n0);
    if (gg < (unsigned)CH) {
      const bool kp = (keys[j] > thr) || ((keys[j] == thr) && (excl + (unsigned)lc[j] < R));
      keep[gg] = kp ? 1.0f : 0.0f;
    }
  }
  __syncthreads();
}

__global__ void __launch_bounds__(NTH)
bdh_main(const int* __restrict__ tokens, const float* __restrict__ spike_u,
         const float* __restrict__ Emat, const float* __restrict__ Dx,
         const float* __restrict__ Dy, const float* __restrict__ temb,
         float* __restrict__ out)
{
  __shared__ float sh_rho[DD][CH+1];   // +1 pad: bank-conflict-free rows
  __shared__ float sh_v[DD];
  __shared__ float sh_xstate[CH];
  __shared__ float sh_xtun[CH];
  __shared__ float sh_xt[CH];
  __shared__ float sh_y[CH];
  __shared__ float sh_yt[CH];
  __shared__ float sh_ahat[DD];
  __shared__ float sh_keep[CH];
  __shared__ float sh_ffac[CH];
  __shared__ unsigned sh_hist[4*256];
  __shared__ unsigned sh_wsum[8];
  __shared__ int sh_misc[4];
  __shared__ float sh_fmisc[4];
  __shared__ double sh_dred[8];

  const int tid = threadIdx.x;
  const int b   = blockIdx.x;
  const int n0  = b * CH;
  const int i4  = tid >> 2;   // local neuron / row index (0..63)
  const int p4  = tid & 3;    // 4-lane split of each 64-long dot
  const int lane = tid & 63;
  unsigned epoch = 0u;

  for (int k = tid; k < DD*(CH+1); k += NTH) (&sh_rho[0][0])[k] = 0.0f;
  if (tid < CH) sh_xstate[tid] = 0.0f;
  __syncthreads();

  for (int t = 0; t < TT; ++t) {
    const int par = t & 1;

    // ---------------- phase 1: x_t (unnorm), L1 partial, rho@x partial ----
    if (tid < DD) {
      const int tok = tokens[t];
      sh_v[tid] = temb[(size_t)tok*DD + tid];
    }
    __syncthreads();
    float d1 = dot16(Dx + ((size_t)(n0+i4))*DD + p4*16, sh_v + p4*16);
    d1 += __shfl_xor(d1, 1, 64);
    d1 += __shfl_xor(d1, 2, 64);
    float xnew = 0.0f;
    if (p4 == 0) {
      xnew = 0.97f * sh_xstate[i4] + fmaxf(d1, 0.0f);
      sh_xtun[i4] = xnew;
    }
    {
      double v = (p4 == 0) ? (double)fabsf(xnew) : 0.0;
      #pragma unroll
      for (int off = 32; off > 0; off >>= 1) v += __shfl_xor(v, off, 64);
      if (lane == 0) sh_dred[tid >> 6] = v;
      __syncthreads();
      if (tid == 0) g_L1[par][b] = sh_dred[0] + sh_dred[1] + sh_dred[2] + sh_dred[3];
    }
    float qa = 0.0f;   // (rho @ x_un) partial; divided by L1 after barrier
    {
      const float* rr = &sh_rho[i4][p4*16];
      const float* xx = &sh_xtun[p4*16];
      #pragma unroll
      for (int j = 0; j < 16; ++j) qa += rr[j] * xx[j];
    }
    qa += __shfl_xor(qa, 1, 64);
    qa += __shfl_xor(qa, 2, 64);
    if (p4 == 0) g_r[par][b][i4] = (double)qa;
    grid_barrier(epoch);                       // ========== A ==========

    // ---------------- phase 2: a_hat, x normalize, y ----------------------
    {
      double v = (tid < NB) ? g_L1[par][tid] : 0.0;
      if (tid < 64) {
        #pragma unroll
        for (int off = 32; off > 0; off >>= 1) v += __shfl_xor(v, off, 64);
        if (tid == 0) sh_dred[0] = v;
      }
      __syncthreads();
    }
    const float Lden = (float)sh_dred[0] + 1e-6f;
    if (tid < DD) {
      double qd = 0.0;
      #pragma unroll 4
      for (int bb = 0; bb < NB; ++bb) qd += g_r[par][bb][tid];
      const float rf = (float)qd / Lden;
      float s1 = rf;
      #pragma unroll
      for (int off = 32; off > 0; off >>= 1) s1 += __shfl_xor(s1, off, 64);
      const float m = s1 * (1.0f/64.0f);
      const float dv = rf - m;
      float s2 = dv * dv;
      #pragma unroll
      for (int off = 32; off > 0; off >>= 1) s2 += __shfl_xor(s2, off, 64);
      const float sd = sqrtf(s2 * (1.0f/63.0f));        // ddof=1
      sh_ahat[tid] = dv / (sd + 1e-6f);
      const float xv = sh_xtun[tid] / Lden;             // elementwise, like ref
      sh_xt[tid] = xv;
      g_xg[par][n0 + tid] = xv;
    }
    __syncthreads();
    float d2 = dot16(Dy + ((size_t)(n0+i4))*DD + p4*16, sh_ahat + p4*16);
    d2 += __shfl_xor(d2, 1, 64);
    d2 += __shfl_xor(d2, 2, 64);
    if (p4 == 0) {
      const float sp = fmaxf(d2, 0.0f) + log1pf(expf(-fabsf(d2)));  // softplus
      const float u  = spike_u[(size_t)t*NN + n0 + i4];
      const float y  = sp + ((u < 0.01f) ? 1.0f : 0.0f);
      sh_y[i4] = y;
      g_yg[par][n0 + i4] = y;
    }
    grid_barrier(epoch);                       // ========== B ==========

    // ---------------- phase 3: k-WTA, y_t, s & E@y_t partials -------------
    select_topk(g_yg[par], KWTA, n0, tid, sh_keep, sh_hist, sh_wsum, sh_misc);
    if (tid < CH) {
      const float ym = sh_keep[tid] * sh_y[tid];
      sh_yt[tid] = fmaxf(ym, 0.0f) * fmaxf(sh_xt[tid], 0.0f);
    }
    __syncthreads();
    float eacc = 0.0f;
    {
      const float* er = Emat + (size_t)i4*NN + n0 + p4*16;
      const float* yy = &sh_yt[p4*16];
      #pragma unroll
      for (int j = 0; j < 16; ++j) eacc += er[j] * yy[j];
    }
    eacc += __shfl_xor(eacc, 1, 64);
    eacc += __shfl_xor(eacc, 2, 64);
    if (p4 == 0) g_e[par][b][i4] = (double)eacc;   // scale applied after sum
    {
      double v = (tid < CH) ? (double)sh_yt[tid] : 0.0;
      #pragma unroll
      for (int off = 32; off > 0; off >>= 1) v += __shfl_xor(v, off, 64);
      if (lane == 0) sh_dred[4 + (tid >> 6)] = v;
      __syncthreads();
      if (tid == 0) g_s[par][b] = sh_dred[4] + sh_dred[5] + sh_dred[6] + sh_dred[7];
    }
    grid_barrier(epoch);                       // ========== C ==========

    // ---------------- phase 4: v_star, gain, dyn mask, rho update ---------
    {
      double v = (tid < NB) ? g_s[par][tid] : 0.0;
      if (tid < 64) {
        #pragma unroll
        for (int off = 32; off > 0; off >>= 1) v += __shfl_xor(v, off, 64);
        if (tid == 0) sh_dred[0] = v;
      }
      __syncthreads();
    }
    const float sf = (float)sh_dred[0];
    const float scale = (sf > 1e-8f) ? fminf(1.0f, 1.0f/(sf + 1e-8f)) : 1.0f;
    if (tid < DD) {
      double ed = 0.0;
      #pragma unroll 4
      for (int bb = 0; bb < NB; ++bb) ed += g_e[par][bb][tid];
      const float z = scale * (float)ed;
      float s1 = z;
      #pragma unroll
      for (int off = 32; off > 0; off >>= 1) s1 += __shfl_xor(s1, off, 64);
      const float m = s1 * (1.0f/64.0f);
      const float dv = z - m;
      float s2 = dv * dv;
      #pragma unroll
      for (int off = 32; off > 0; off >>= 1) s2 += __shfl_xor(s2, off, 64);
      const float sd = sqrtf(s2 * (1.0f/63.0f));
      const float vs = dv / (sd + 1e-6f);
      if (b == 0) out[t*DD + tid] = vs;
      float mx = vs;
      #pragma unroll
      for (int off = 32; off > 0; off >>= 1) mx = fmaxf(mx, __shfl_xor(mx, off, 64));
      const float ex = expf(vs - mx);
      float se = ex;
      #pragma unroll
      for (int off = 32; off > 0; off >>= 1) se += __shfl_xor(se, off, 64);
      const float pp = ex / se;
      float ht = -pp * logf(pp + 1e-12f);
      #pragma unroll
      for (int off = 32; off > 0; off >>= 1) ht += __shfl_xor(ht, off, 64);
      if (tid == 0) sh_fmisc[0] = fminf(1.0f, ht / logf(64.0f));
    }
    __syncthreads();
    const float gain = sh_fmisc[0];
    int kd = (int)(2048.0f * (0.05f + 0.25f * gain));
    kd = kd < 1 ? 1 : (kd > NN ? NN : kd);
    select_topk(g_xg[par], kd, n0, tid, sh_keep, sh_hist, sh_wsum, sh_misc);
    if (tid < CH) {
      const float xm = sh_keep[tid] * sh_xt[tid];
      sh_xstate[tid] = xm;
      sh_ffac[tid] = (xm <= 0.0f) ? (1.0f - 0.01f) : 1.0f;
    }
    __syncthreads();
    {
      const float vd = sh_v[i4];
      float* rr = &sh_rho[i4][p4*16];
      const float* xx = &sh_xstate[p4*16];
      const float* ff = &sh_ffac[p4*16];
      #pragma unroll
      for (int j = 0; j < 16; ++j)
        rr[j] = 0.97f * (rr[j]*ff[j] + gain * (vd * xx[j]));
    }
    __syncthreads();   // protect sh_v/sh_xstate/rho before next iteration
  }
}

extern "C" void kernel_launch(void* const* d_in, const int* in_sizes, int n_in,
                              void* d_out, int out_size, void* d_ws, size_t ws_size,
                              hipStream_t stream) {
  const int*   tokens = (const int*)d_in[0];
  const float* spike  = (const float*)d_in[1];
  const float* Emat   = (const float*)d_in[2];
  const float* Dx     = (const float*)d_in[3];
  const float* Dy     = (const float*)d_in[4];
  const float* temb   = (const float*)d_in[5];
  float* out = (float*)d_out;
  (void)in_sizes; (void)n_in; (void)out_size; (void)d_ws; (void)ws_size;
  bdh_init<<<dim3(1), dim3(64), 0, stream>>>();
  bdh_main<<<dim3(NB), dim3(NTH), 0, stream>>>(tokens, spike, Emat, Dx, Dy, temb, out);
}

// Round 2
// 11341.470 us; speedup vs baseline: 1.2275x; 1.2275x over previous
//
#include <hip/hip_runtime.h>
#include <math.h>

#define NB   32      // blocks
#define NTH  256     // threads per block
#define CH   64      // neurons per block (N/NB)
#define NN   2048    // N
#define DD   64      // D
#define TT   512     // T
#define KWTA 256
#define PAD  65      // LDS row pad (floats): bank-conflict-free 2-way pattern

// Cross-block communication buffers (ping-pong on step parity).
__device__ __align__(16) double g_L1[2][NB];
__device__ __align__(16) double g_r [2][NB][DD];
__device__ __align__(16) double g_s [2][NB];
__device__ __align__(16) double g_e [2][NB][DD];
__device__ __align__(16) float  g_xg[2][NN];
__device__ __align__(16) float  g_yg[2][NN];
__device__ unsigned g_bar;

__global__ void bdh_init() { if (threadIdx.x == 0) g_bar = 0u; }

// Grid barrier: one release writeback on arrival, RELAXED polling (no
// buffer_inv per poll!), one acquire fence on exit.
__device__ __forceinline__ void grid_barrier(unsigned& epoch) {
  __syncthreads();
  if (threadIdx.x == 0) {
    epoch += 1u;
    __threadfence();  // release: make this block's writes visible device-wide
    __hip_atomic_fetch_add(&g_bar, 1u, __ATOMIC_RELAXED, __HIP_MEMORY_SCOPE_AGENT);
    const unsigned target = epoch * (unsigned)NB;
    while (__hip_atomic_load(&g_bar, __ATOMIC_RELAXED, __HIP_MEMORY_SCOPE_AGENT) < target)
      __builtin_amdgcn_s_sleep(1);
    __builtin_amdgcn_fence(__ATOMIC_ACQUIRE, "agent");  // one cache invalidate
  }
  __syncthreads();
}

// Exact top-K threshold + stable (lowest-index-first) tie mask over 2048
// nonnegative floats whose bit patterns are preloaded in keys[8]
// (key j of thread tid = element tid*8+j). Fills keep[0..CH) for global
// indices [n0, n0+CH). Radix select on float bits (nonneg floats = uint order).
__device__ void select_topk(const unsigned* __restrict__ keys, int K, int n0, int tid,
                            float* __restrict__ keep,
                            unsigned* __restrict__ hist,   // LDS [256*8] sub-banked
                            unsigned* __restrict__ wsum,   // LDS [8]
                            int* __restrict__ misc)        // LDS [4]
{
  const int wave = tid >> 6, lane = tid & 63;
  const int sub = tid & 7;          // spread same-bucket atomics over 8 slots
  uint4* h4 = (uint4*)hist;
  unsigned prefix = 0u, pmask = 0u;
  int remK = K;
  for (int lev = 0; lev < 4; ++lev) {
    const int shf = 24 - 8*lev;
    const uint4 z = {0u,0u,0u,0u};
    h4[tid] = z; h4[tid + 256] = z;
    __syncthreads();
    #pragma unroll
    for (int j = 0; j < 8; ++j)
      if ((keys[j] & pmask) == prefix)
        atomicAdd(&hist[(((keys[j] >> shf) & 255u) << 3) + sub], 1u);
    __syncthreads();
    const uint4 a = h4[tid*2], bq = h4[tid*2 + 1];
    const unsigned c = a.x+a.y+a.z+a.w + bq.x+bq.y+bq.z+bq.w;
    unsigned s = c;  // inclusive suffix sum over bucket index (= tid)
    #pragma unroll
    for (int off = 1; off < 64; off <<= 1) {
      unsigned o = __shfl_down(s, off, 64);
      if (lane + off < 64) s += o;
    }
    if (lane == 0) wsum[wave] = s;
    __syncthreads();
    unsigned hi = 0;
    for (int w = wave + 1; w < 4; ++w) hi += wsum[w];
    const unsigned A = s + hi;       // count of keys with bucket >= tid
    if (A >= (unsigned)remK && (A - c) < (unsigned)remK) {  // unique crossing
      misc[0] = tid;
      misc[1] = remK - (int)(A - c);
    }
    __syncthreads();
    prefix |= ((unsigned)misc[0]) << shf;
    pmask  |= (255u << shf);
    remK = misc[1];
    // no extra sync: next writes to hist/misc are >=1 syncthreads away
  }
  const unsigned thr = prefix;
  const unsigned R = (unsigned)remK;   // # of thr-equal entries kept (lowest idx first)
  int lc[8]; int cnt = 0;
  #pragma unroll
  for (int j = 0; j < 8; ++j) { lc[j] = cnt; cnt += (keys[j] == thr) ? 1 : 0; }
  unsigned e = (unsigned)cnt;          // stable rank among equals
  #pragma unroll
  for (int off = 1; off < 64; off <<= 1) {
    unsigned o = __shfl_up(e, off, 64);
    if (lane >= off) e += o;
  }
  if (lane == 63) wsum[4 + wave] = e;
  __syncthreads();
  unsigned base = 0;
  for (int w = 0; w < wave; ++w) base += wsum[4 + w];
  const unsigned excl = base + e - (unsigned)cnt;
  #pragma unroll
  for (int j = 0; j < 8; ++j) {
    const int g = tid*8 + j;
    const unsigned gg = (unsigned)(g - n0);
    if (gg < (unsigned)CH) {
      const bool kp = (keys[j] > thr) || ((keys[j] == thr) && (excl + (unsigned)lc[j] < R));
      keep[gg] = kp ? 1.0f : 0.0f;
    }
  }
  __syncthreads();
}

__global__ void __launch_bounds__(NTH)
bdh_main(const int* __restrict__ tokens, const float* __restrict__ spike_u,
         const float* __restrict__ Emat, const float* __restrict__ Dx,
         const float* __restrict__ Dy, const float* __restrict__ temb,
         float* __restrict__ out)
{
  __shared__ float sh_rho[DD][PAD];
  __shared__ float sh_Dx[CH][PAD];   // [local neuron][d]
  __shared__ float sh_Dy[CH][PAD];   // [local neuron][d]
  __shared__ float sh_E [DD][PAD];   // [d][local neuron]
  __shared__ int   sh_tok[TT];
  __shared__ float sh_v[2][DD];
  __shared__ float sh_xstate[CH];
  __shared__ float sh_xtun[CH];
  __shared__ float sh_xt[CH];
  __shared__ float sh_y[CH];
  __shared__ float sh_yt[CH];
  __shared__ float sh_ahat[DD];
  __shared__ float sh_keep[CH];
  __shared__ float sh_ffac[CH];
  __shared__ unsigned sh_hist[256*8];
  __shared__ unsigned sh_wsum[8];
  __shared__ int sh_misc[4];
  __shared__ float sh_fmisc[4];
  __shared__ double sh_dred[8];
  __shared__ double sh_rd[4][DD];

  const int tid = threadIdx.x;
  const int b   = blockIdx.x;
  const int n0  = b * CH;
  const int i4  = tid >> 2;   // local neuron / row index (0..63)
  const int p4  = tid & 3;    // 4-lane split of each 64-long dot
  const int lane = tid & 63;
  const int wv   = tid >> 6;
  unsigned epoch = 0u;

  // ---- one-time init: tokens, rho=0, weight slices -> LDS ----
  for (int k = tid; k < TT; k += NTH) sh_tok[k] = tokens[k];
  for (int k = tid; k < DD*PAD; k += NTH) (&sh_rho[0][0])[k] = 0.0f;
  if (tid < CH) sh_xstate[tid] = 0.0f;
  for (int r = wv; r < CH; r += 4) {          // 4 waves x 64 lanes, coalesced
    sh_Dx[r][lane] = Dx[(size_t)(n0 + r)*DD + lane];
    sh_Dy[r][lane] = Dy[(size_t)(n0 + r)*DD + lane];
    sh_E [r][lane] = Emat[(size_t)r*NN + n0 + lane];
  }
  __syncthreads();
  if (tid < DD) sh_v[0][tid] = temb[(size_t)sh_tok[0]*DD + tid];
  __syncthreads();

  for (int t = 0; t < TT; ++t) {
    const int par = t & 1;

    // ---------------- phase 1: x_t (unnorm), L1 partial, rho@x partial ----
    // early issue: spike row (used phase 2) + next token's embedding row
    const float spu = spike_u[(size_t)t*NN + n0 + i4];
    if (t + 1 < TT && tid < DD)
      sh_v[(t + 1) & 1][tid] = temb[(size_t)sh_tok[t + 1]*DD + tid];

    float d1 = 0.0f;
    {
      const float* dxr = &sh_Dx[i4][p4*16];
      const float* vv  = &sh_v[par][p4*16];
      #pragma unroll
      for (int j = 0; j < 16; ++j) d1 += dxr[j] * vv[j];
    }
    d1 += __shfl_xor(d1, 1, 64);
    d1 += __shfl_xor(d1, 2, 64);
    float xnew = 0.0f;
    if (p4 == 0) {
      xnew = 0.97f * sh_xstate[i4] + fmaxf(d1, 0.0f);
      sh_xtun[i4] = xnew;
    }
    {
      double v = (p4 == 0) ? (double)fabsf(xnew) : 0.0;
      #pragma unroll
      for (int off = 32; off > 0; off >>= 1) v += __shfl_xor(v, off, 64);
      if (lane == 0) sh_dred[wv] = v;
      __syncthreads();
      if (tid == 0) g_L1[par][b] = sh_dred[0] + sh_dred[1] + sh_dred[2] + sh_dred[3];
    }
    float qa = 0.0f;   // (rho @ x_un) partial; divided by L1 after barrier
    {
      const float* rr = &sh_rho[i4][p4*16];
      const float* xx = &sh_xtun[p4*16];
      #pragma unroll
      for (int j = 0; j < 16; ++j) qa += rr[j] * xx[j];
    }
    qa += __shfl_xor(qa, 1, 64);
    qa += __shfl_xor(qa, 2, 64);
    if (p4 == 0) g_r[par][b][i4] = (double)qa;
    grid_barrier(epoch);                       // ========== A ==========

    // ---------------- phase 2: a_hat, x normalize, y ----------------------
    // parallel cross-block reduction: wave wv sums blocks [8wv, 8wv+8)
    {
      double acc = 0.0;
      #pragma unroll
      for (int j = 0; j < 8; ++j) acc += g_r[par][wv*8 + j][lane];
      sh_rd[wv][lane] = acc;
    }
    {
      double v = (tid < NB) ? g_L1[par][tid] : 0.0;
      if (tid < 64) {
        #pragma unroll
        for (int off = 32; off > 0; off >>= 1) v += __shfl_xor(v, off, 64);
        if (tid == 0) sh_dred[0] = v;
      }
    }
    __syncthreads();
    const float Lden = (float)sh_dred[0] + 1e-6f;
    if (tid < DD) {
      const double qd = sh_rd[0][tid] + sh_rd[1][tid] + sh_rd[2][tid] + sh_rd[3][tid];
      const float rf = (float)qd / Lden;
      float s1 = rf;
      #pragma unroll
      for (int off = 32; off > 0; off >>= 1) s1 += __shfl_xor(s1, off, 64);
      const float m = s1 * (1.0f/64.0f);
      const float dv = rf - m;
      float s2 = dv * dv;
      #pragma unroll
      for (int off = 32; off > 0; off >>= 1) s2 += __shfl_xor(s2, off, 64);
      const float sd = sqrtf(s2 * (1.0f/63.0f));        // ddof=1
      sh_ahat[tid] = dv / (sd + 1e-6f);
      const float xv = sh_xtun[tid] / Lden;             // elementwise, like ref
      sh_xt[tid] = xv;
      g_xg[par][n0 + tid] = xv;
    }
    __syncthreads();
    float d2 = 0.0f;
    {
      const float* dyr = &sh_Dy[i4][p4*16];
      const float* aa  = &sh_ahat[p4*16];
      #pragma unroll
      for (int j = 0; j < 16; ++j) d2 += dyr[j] * aa[j];
    }
    d2 += __shfl_xor(d2, 1, 64);
    d2 += __shfl_xor(d2, 2, 64);
    if (p4 == 0) {
      const float sp = fmaxf(d2, 0.0f) + log1pf(expf(-fabsf(d2)));  // softplus
      const float y  = sp + ((spu < 0.01f) ? 1.0f : 0.0f);
      sh_y[i4] = y;
      g_yg[par][n0 + i4] = y;
    }
    grid_barrier(epoch);                       // ========== B ==========

    // ---------------- phase 3: k-WTA, y_t, s & E@y_t partials -------------
    // preload keys for BOTH selects (g_xg is final as of barrier B)
    unsigned ykeys[8], xkeys[8];
    {
      const float4* py = ((const float4*)g_yg[par]) + tid*2;
      const float4* px = ((const float4*)g_xg[par]) + tid*2;
      float4 y0 = py[0], y1 = py[1];
      float4 x0 = px[0], x1 = px[1];
      ykeys[0]=__float_as_uint(y0.x); ykeys[1]=__float_as_uint(y0.y);
      ykeys[2]=__float_as_uint(y0.z); ykeys[3]=__float_as_uint(y0.w);
      ykeys[4]=__float_as_uint(y1.x); ykeys[5]=__float_as_uint(y1.y);
      ykeys[6]=__float_as_uint(y1.z); ykeys[7]=__float_as_uint(y1.w);
      xkeys[0]=__float_as_uint(x0.x); xkeys[1]=__float_as_uint(x0.y);
      xkeys[2]=__float_as_uint(x0.z); xkeys[3]=__float_as_uint(x0.w);
      xkeys[4]=__float_as_uint(x1.x); xkeys[5]=__float_as_uint(x1.y);
      xkeys[6]=__float_as_uint(x1.z); xkeys[7]=__float_as_uint(x1.w);
    }
    select_topk(ykeys, KWTA, n0, tid, sh_keep, sh_hist, sh_wsum, sh_misc);
    if (tid < CH) {
      const float ym = sh_keep[tid] * sh_y[tid];
      sh_yt[tid] = fmaxf(ym, 0.0f) * fmaxf(sh_xt[tid], 0.0f);
    }
    __syncthreads();
    float eacc = 0.0f;
    {
      const float* er = &sh_E[i4][p4*16];
      const float* yy = &sh_yt[p4*16];
      #pragma unroll
      for (int j = 0; j < 16; ++j) eacc += er[j] * yy[j];
    }
    eacc += __shfl_xor(eacc, 1, 64);
    eacc += __shfl_xor(eacc, 2, 64);
    if (p4 == 0) g_e[par][b][i4] = (double)eacc;   // scale applied after sum
    {
      double v = (tid < CH) ? (double)sh_yt[tid] : 0.0;
      #pragma unroll
      for (int off = 32; off > 0; off >>= 1) v += __shfl_xor(v, off, 64);
      if (lane == 0) sh_dred[4 + wv] = v;
      __syncthreads();
      if (tid == 0) g_s[par][b] = sh_dred[4] + sh_dred[5] + sh_dred[6] + sh_dred[7];
    }
    grid_barrier(epoch);                       // ========== C ==========

    // ---------------- phase 4: v_star, gain, dyn mask, rho update ---------
    {
      double acc = 0.0;
      #pragma unroll
      for (int j = 0; j < 8; ++j) acc += g_e[par][wv*8 + j][lane];
      sh_rd[wv][lane] = acc;
    }
    {
      double v = (tid < NB) ? g_s[par][tid] : 0.0;
      if (tid < 64) {
        #pragma unroll
        for (int off = 32; off > 0; off >>= 1) v += __shfl_xor(v, off, 64);
        if (tid == 0) sh_dred[0] = v;
      }
    }
    __syncthreads();
    const float sf = (float)sh_dred[0];
    const float scale = (sf > 1e-8f) ? fminf(1.0f, 1.0f/(sf + 1e-8f)) : 1.0f;
    if (tid < DD) {
      const double ed = sh_rd[0][tid] + sh_rd[1][tid] + sh_rd[2][tid] + sh_rd[3][tid];
      const float z = scale * (float)ed;
      float s1 = z;
      #pragma unroll
      for (int off = 32; off > 0; off >>= 1) s1 += __shfl_xor(s1, off, 64);
      const float m = s1 * (1.0f/64.0f);
      const float dv = z - m;
      float s2 = dv * dv;
      #pragma unroll
      for (int off = 32; off > 0; off >>= 1) s2 += __shfl_xor(s2, off, 64);
      const float sd = sqrtf(s2 * (1.0f/63.0f));
      const float vs = dv / (sd + 1e-6f);
      if (b == 0) out[t*DD + tid] = vs;
      float mx = vs;
      #pragma unroll
      for (int off = 32; off > 0; off >>= 1) mx = fmaxf(mx, __shfl_xor(mx, off, 64));
      const float ex = expf(vs - mx);
      float se = ex;
      #pragma unroll
      for (int off = 32; off > 0; off >>= 1) se += __shfl_xor(se, off, 64);
      const float pp = ex / se;
      float ht = -pp * logf(pp + 1e-12f);
      #pragma unroll
      for (int off = 32; off > 0; off >>= 1) ht += __shfl_xor(ht, off, 64);
      if (tid == 0) sh_fmisc[0] = fminf(1.0f, ht / logf(64.0f));
    }
    __syncthreads();
    const float gain = sh_fmisc[0];
    int kd = (int)(2048.0f * (0.05f + 0.25f * gain));
    kd = kd < 1 ? 1 : (kd > NN ? NN : kd);
    select_topk(xkeys, kd, n0, tid, sh_keep, sh_hist, sh_wsum, sh_misc);
    if (tid < CH) {
      const float xm = sh_keep[tid] * sh_xt[tid];
      sh_xstate[tid] = xm;
      sh_ffac[tid] = (xm <= 0.0f) ? (1.0f - 0.01f) : 1.0f;
    }
    __syncthreads();
    {
      const float vd = sh_v[par][i4];
      float* rr = &sh_rho[i4][p4*16];
      const float* xx = &sh_xstate[p4*16];
      const float* ff = &sh_ffac[p4*16];
      #pragma unroll
      for (int j = 0; j < 16; ++j)
        rr[j] = 0.97f * (rr[j]*ff[j] + gain * (vd * xx[j]));
    }
    __syncthreads();   // protect sh_v/sh_xstate/rho before next iteration
  }
}

extern "C" void kernel_launch(void* const* d_in, const int* in_sizes, int n_in,
                              void* d_out, int out_size, void* d_ws, size_t ws_size,
                              hipStream_t stream) {
  const int*   tokens = (const int*)d_in[0];
  const float* spike  = (const float*)d_in[1];
  const float* Emat   = (const float*)d_in[2];
  const float* Dx     = (const float*)d_in[3];
  const float* Dy     = (const float*)d_in[4];
  const float* temb   = (const float*)d_in[5];
  float* out = (float*)d_out;
  (void)in_sizes; (void)n_in; (void)out_size; (void)d_ws; (void)ws_size;
  bdh_init<<<dim3(1), dim3(64), 0, stream>>>();
  bdh_main<<<dim3(NB), dim3(NTH), 0, stream>>>(tokens, spike, Emat, Dx, Dy, temb, out);
}

// Round 3
// 9784.220 us; speedup vs baseline: 1.4229x; 1.1592x over previous
//
#include <hip/hip_runtime.h>
#include <math.h>

#define NB   16      // blocks
#define NTH  256     // threads per block
#define CH   128     // neurons per block (N/NB)
#define NN   2048    // N
#define DD   64      // D
#define TT   512     // T
#define KWTA 256
#define PA   65      // pad for [CH][64+1] rows (Dx, Dy): odd pad -> 2-way-free
#define PB   132     // pad for [64][128+4] rows (rho, E): comb access 2-way-free

// ---- cross-block communication (single-buffered; WAR-safe by barrier deps) --
struct __align__(128) BarFlag { unsigned v; unsigned pad[31]; };
__device__ BarFlag g_flag[NB];
__device__ __align__(16) float  g_rf[NB][DD];   // rho@x_un partials
__device__ __align__(16) float  g_ef[NB][DD];   // E@y_t partials
__device__ __align__(16) double g_L1[NB];
__device__ __align__(16) double g_s [NB];
__device__ __align__(16) float  g_xg[NN];
__device__ __align__(16) float  g_yg[NN];

__global__ void bdh_init() { if (threadIdx.x < NB) g_flag[threadIdx.x].v = 0u; }

// Distributed-flag grid barrier: each block release-stores its own monotonic
// epoch flag (own 128B line, no RMW contention); wave 0 polls all flags with
// relaxed loads; one acquire fence on exit (round-2-proven memory discipline).
__device__ __forceinline__ void grid_barrier(unsigned& epoch) {
  epoch += 1u;
  __syncthreads();
  if (threadIdx.x < 64) {
    if (threadIdx.x == 0) {
      __threadfence();  // release: flush this block's writes device-wide
      __hip_atomic_store(&g_flag[blockIdx.x].v, epoch, __ATOMIC_RELAXED,
                         __HIP_MEMORY_SCOPE_AGENT);
    }
    const int i = (int)threadIdx.x;
    for (;;) {
      const bool ok = (i >= NB) ||
        (__hip_atomic_load(&g_flag[i].v, __ATOMIC_RELAXED,
                           __HIP_MEMORY_SCOPE_AGENT) >= epoch);
      if (__all(ok)) break;
      __builtin_amdgcn_s_sleep(1);
    }
    __builtin_amdgcn_fence(__ATOMIC_ACQUIRE, "agent");  // one invalidate
  }
  __syncthreads();
}

__device__ __forceinline__ double wredd(double v) {
  #pragma unroll
  for (int off = 32; off > 0; off >>= 1) v += __shfl_xor(v, off, 64);
  return v;
}
__device__ __forceinline__ float wredf(float v) {
  #pragma unroll
  for (int off = 32; off > 0; off >>= 1) v += __shfl_xor(v, off, 64);
  return v;
}

// Exact top-K threshold + stable (lowest-index-first) tie mask over 2048
// nonnegative floats (bit patterns preloaded in keys[8]; key j of thread tid
// = element tid*8+j). Fills keep[0..CH) for global indices [n0, n0+CH).
__device__ void select_topk(const unsigned* __restrict__ keys, int K, int n0, int tid,
                            float* __restrict__ keep,
                            unsigned* __restrict__ hist,   // LDS [256*8] sub-banked
                            unsigned* __restrict__ wsum,   // LDS [8]
                            int* __restrict__ misc)        // LDS [4]
{
  const int wave = tid >> 6, lane = tid & 63;
  const int sub = tid & 7;          // spread same-bucket atomics over 8 slots
  uint4* h4 = (uint4*)hist;
  unsigned prefix = 0u, pmask = 0u;
  int remK = K;
  for (int lev = 0; lev < 4; ++lev) {
    const int shf = 24 - 8*lev;
    const uint4 z = {0u,0u,0u,0u};
    h4[tid] = z; h4[tid + 256] = z;
    __syncthreads();
    #pragma unroll
    for (int j = 0; j < 8; ++j)
      if ((keys[j] & pmask) == prefix)
        atomicAdd(&hist[(((keys[j] >> shf) & 255u) << 3) + sub], 1u);
    __syncthreads();
    const uint4 a = h4[tid*2], bq = h4[tid*2 + 1];
    const unsigned c = a.x+a.y+a.z+a.w + bq.x+bq.y+bq.z+bq.w;
    unsigned s = c;  // inclusive suffix sum over bucket index (= tid)
    #pragma unroll
    for (int off = 1; off < 64; off <<= 1) {
      unsigned o = __shfl_down(s, off, 64);
      if (lane + off < 64) s += o;
    }
    if (lane == 0) wsum[wave] = s;
    __syncthreads();
    unsigned hi = 0;
    for (int w = wave + 1; w < 4; ++w) hi += wsum[w];
    const unsigned A = s + hi;       // count of keys with bucket >= tid
    if (A >= (unsigned)remK && (A - c) < (unsigned)remK) {  // unique crossing
      misc[0] = tid;
      misc[1] = remK - (int)(A - c);
    }
    __syncthreads();
    prefix |= ((unsigned)misc[0]) << shf;
    pmask  |= (255u << shf);
    remK = misc[1];
  }
  const unsigned thr = prefix;
  const unsigned R = (unsigned)remK;   // # of thr-equal entries kept
  int lc[8]; int cnt = 0;
  #pragma unroll
  for (int j = 0; j < 8; ++j) { lc[j] = cnt; cnt += (keys[j] == thr) ? 1 : 0; }
  unsigned e = (unsigned)cnt;          // stable rank among equals
  #pragma unroll
  for (int off = 1; off < 64; off <<= 1) {
    unsigned o = __shfl_up(e, off, 64);
    if (lane >= off) e += o;
  }
  if (lane == 63) wsum[4 + wave] = e;
  __syncthreads();
  unsigned base = 0;
  for (int w = 0; w < wave; ++w) base += wsum[4 + w];
  const unsigned excl = base + e - (unsigned)cnt;
  #pragma unroll
  for (int j = 0; j < 8; ++j) {
    const int g = tid*8 + j;
    const unsigned gg = (unsigned)(g - n0);
    if (gg < (unsigned)CH) {
      const bool kp = (keys[j] > thr) || ((keys[j] == thr) && (excl + (unsigned)lc[j] < R));
      keep[gg] = kp ? 1.0f : 0.0f;
    }
  }
  __syncthreads();
}

__global__ void __launch_bounds__(NTH)
bdh_main(const int* __restrict__ tokens, const float* __restrict__ spike_u,
         const float* __restrict__ Emat, const float* __restrict__ Dx,
         const float* __restrict__ Dy, const float* __restrict__ temb,
         float* __restrict__ out)
{
  __shared__ float sh_rho[DD][PB];   // [d][local col]
  __shared__ float sh_Dx[CH][PA];    // [local neuron][d]
  __shared__ float sh_Dy[CH][PA];
  __shared__ float sh_E [DD][PB];    // [d][local col]
  __shared__ int   sh_tok[TT];
  __shared__ float sh_v[2][DD];
  __shared__ float sh_xstate[CH];
  __shared__ float sh_xtun[CH];
  __shared__ float sh_xt[CH];
  __shared__ float sh_y[CH];
  __shared__ float sh_yt[CH];
  __shared__ float sh_ahat[DD];
  __shared__ float sh_keep[CH];
  __shared__ float sh_ffac[CH];
  __shared__ unsigned sh_hist[256*8];
  __shared__ unsigned sh_wsum[8];
  __shared__ int sh_misc[4];
  __shared__ float sh_fmisc[4];
  __shared__ double sh_dred[8];
  __shared__ double sh_rd[4][DD];

  const int tid  = threadIdx.x;
  const int b    = blockIdx.x;
  const int n0   = b * CH;
  const int i2   = tid >> 1;   // local neuron row (0..127), Dx/Dy mapping
  const int p2   = tid & 1;    // half-split of 64-dot
  const int d4   = tid >> 2;   // d row (0..63), rho/E mapping
  const int p4   = tid & 3;    // quarter-comb of 128-dot
  const int lane = tid & 63;
  const int wv   = tid >> 6;
  unsigned epoch = 0u;

  // ---- one-time init: tokens, rho=0, weight slices -> LDS ----
  for (int k = tid; k < TT; k += NTH) sh_tok[k] = tokens[k];
  for (int k = tid; k < DD*PB; k += NTH) (&sh_rho[0][0])[k] = 0.0f;
  if (tid < CH) sh_xstate[tid] = 0.0f;
  for (int r = wv; r < CH; r += 4) {
    sh_Dx[r][lane] = Dx[(size_t)(n0 + r)*DD + lane];
    sh_Dy[r][lane] = Dy[(size_t)(n0 + r)*DD + lane];
  }
  for (int r = wv; r < DD; r += 4) {
    sh_E[r][lane]      = Emat[(size_t)r*NN + n0 + lane];
    sh_E[r][lane + 64] = Emat[(size_t)r*NN + n0 + lane + 64];
  }
  __syncthreads();
  if (tid < DD) sh_v[0][tid] = temb[(size_t)sh_tok[0]*DD + tid];
  __syncthreads();

  for (int t = 0; t < TT; ++t) {
    const int par = t & 1;

    // -------- phase 1: x_t (unnorm), L1 partial, rho@x partial ------------
    float spu = 0.0f;
    if (p2 == 0) spu = spike_u[(size_t)t*NN + n0 + i2];   // used in phase 2
    if (t + 1 < TT && tid < DD)
      sh_v[par ^ 1][tid] = temb[(size_t)sh_tok[t + 1]*DD + tid];

    float d1 = 0.0f;
    {
      const float* dxr = &sh_Dx[i2][p2*32];
      const float* vv  = &sh_v[par][p2*32];
      #pragma unroll
      for (int j = 0; j < 32; ++j) d1 += dxr[j] * vv[j];
    }
    d1 += __shfl_xor(d1, 1, 64);
    float xnew = 0.0f;
    if (p2 == 0) {
      xnew = 0.97f * sh_xstate[i2] + fmaxf(d1, 0.0f);
      sh_xtun[i2] = xnew;
    }
    {
      double v = (p2 == 0) ? (double)fabsf(xnew) : 0.0;
      v = wredd(v);
      if (lane == 0) sh_dred[wv] = v;
      __syncthreads();
      if (tid == 0) g_L1[b] = sh_dred[0] + sh_dred[1] + sh_dred[2] + sh_dred[3];
    }
    float qa = 0.0f;   // (rho @ x_un) partial over this block's 128 cols
    {
      const float* rr = &sh_rho[d4][0];
      #pragma unroll
      for (int j = 0; j < 32; ++j) { const int c = p4 + 4*j; qa += rr[c] * sh_xtun[c]; }
    }
    qa += __shfl_xor(qa, 1, 64);
    qa += __shfl_xor(qa, 2, 64);
    if (p4 == 0) g_rf[b][d4] = qa;
    grid_barrier(epoch);                       // ========== A ==========

    // -------- phase 2: a_hat (wave0) || x normalize (waves 1-2), y --------
    {
      double acc = 0.0;
      #pragma unroll
      for (int j = 0; j < 4; ++j) acc += (double)g_rf[(wv<<2) + j][lane];
      sh_rd[wv][lane] = acc;
    }
    if (tid < 64) {
      double v = (tid < NB) ? g_L1[tid] : 0.0;
      v = wredd(v);
      if (tid == 0) sh_dred[0] = v;
    }
    __syncthreads();
    const float Lden = (float)sh_dred[0] + 1e-6f;
    if (tid < 64) {
      const double qd = sh_rd[0][tid] + sh_rd[1][tid] + sh_rd[2][tid] + sh_rd[3][tid];
      const float rf = (float)qd / Lden;
      const float m  = wredf(rf) * (1.0f/64.0f);
      const float dv = rf - m;
      const float sd = sqrtf(wredf(dv*dv) * (1.0f/63.0f));   // ddof=1
      sh_ahat[tid] = dv / (sd + 1e-6f);
    } else if (tid < 192) {
      const int l = tid - 64;
      const float xv = sh_xtun[l] / Lden;
      sh_xt[l] = xv;
      g_xg[n0 + l] = xv;
    }
    __syncthreads();
    float d2 = 0.0f;
    {
      const float* dyr = &sh_Dy[i2][p2*32];
      const float* aa  = &sh_ahat[p2*32];
      #pragma unroll
      for (int j = 0; j < 32; ++j) d2 += dyr[j] * aa[j];
    }
    d2 += __shfl_xor(d2, 1, 64);
    if (p2 == 0) {
      const float sp = fmaxf(d2, 0.0f) + log1pf(expf(-fabsf(d2)));  // softplus
      const float y  = sp + ((spu < 0.01f) ? 1.0f : 0.0f);
      sh_y[i2] = y;
      g_yg[n0 + i2] = y;
    }
    grid_barrier(epoch);                       // ========== B ==========

    // -------- phase 3: k-WTA, y_t, s & E@y_t partials ---------------------
    unsigned ykeys[8], xkeys[8];
    {
      const float4* py = ((const float4*)g_yg) + tid*2;
      const float4* px = ((const float4*)g_xg) + tid*2;
      float4 y0 = py[0], y1 = py[1];
      float4 x0 = px[0], x1 = px[1];
      ykeys[0]=__float_as_uint(y0.x); ykeys[1]=__float_as_uint(y0.y);
      ykeys[2]=__float_as_uint(y0.z); ykeys[3]=__float_as_uint(y0.w);
      ykeys[4]=__float_as_uint(y1.x); ykeys[5]=__float_as_uint(y1.y);
      ykeys[6]=__float_as_uint(y1.z); ykeys[7]=__float_as_uint(y1.w);
      xkeys[0]=__float_as_uint(x0.x); xkeys[1]=__float_as_uint(x0.y);
      xkeys[2]=__float_as_uint(x0.z); xkeys[3]=__float_as_uint(x0.w);
      xkeys[4]=__float_as_uint(x1.x); xkeys[5]=__float_as_uint(x1.y);
      xkeys[6]=__float_as_uint(x1.z); xkeys[7]=__float_as_uint(x1.w);
    }
    select_topk(ykeys, KWTA, n0, tid, sh_keep, sh_hist, sh_wsum, sh_misc);
    if (tid < CH) {
      const float ym = sh_keep[tid] * sh_y[tid];
      sh_yt[tid] = fmaxf(ym, 0.0f) * fmaxf(sh_xt[tid], 0.0f);
    }
    __syncthreads();
    float ea = 0.0f;
    {
      const float* er = &sh_E[d4][0];
      #pragma unroll
      for (int j = 0; j < 32; ++j) { const int c = p4 + 4*j; ea += er[c] * sh_yt[c]; }
    }
    ea += __shfl_xor(ea, 1, 64);
    ea += __shfl_xor(ea, 2, 64);
    if (p4 == 0) g_ef[b][d4] = ea;   // homeostasis scale applied after sum
    {
      double v = (tid < CH) ? (double)sh_yt[tid] : 0.0;
      v = wredd(v);
      if (lane == 0) sh_dred[4 + wv] = v;
      __syncthreads();
      if (tid == 0) g_s[b] = sh_dred[4] + sh_dred[5] + sh_dred[6] + sh_dred[7];
    }
    grid_barrier(epoch);                       // ========== C ==========

    // -------- phase 4: v_star, gain, dyn mask, rho update -----------------
    {
      double acc = 0.0;
      #pragma unroll
      for (int j = 0; j < 4; ++j) acc += (double)g_ef[(wv<<2) + j][lane];
      sh_rd[wv][lane] = acc;
    }
    if (tid < 64) {
      double v = (tid < NB) ? g_s[tid] : 0.0;
      v = wredd(v);
      if (tid == 0) sh_dred[0] = v;
    }
    __syncthreads();
    const float sf = (float)sh_dred[0];
    const float scale = (sf > 1e-8f) ? fminf(1.0f, 1.0f/(sf + 1e-8f)) : 1.0f;
    if (tid < 64) {
      const double ed = sh_rd[0][tid] + sh_rd[1][tid] + sh_rd[2][tid] + sh_rd[3][tid];
      const float z = scale * (float)ed;
      const float m  = wredf(z) * (1.0f/64.0f);
      const float dv = z - m;
      const float sd = sqrtf(wredf(dv*dv) * (1.0f/63.0f));
      const float vs = dv / (sd + 1e-6f);
      if (b == 0) out[t*DD + tid] = vs;
      float mx = vs;
      #pragma unroll
      for (int off = 32; off > 0; off >>= 1) mx = fmaxf(mx, __shfl_xor(mx, off, 64));
      const float ex = expf(vs - mx);
      const float se = wredf(ex);
      const float pp = ex / se;
      const float ht = wredf(-pp * logf(pp + 1e-12f));
      if (tid == 0) sh_fmisc[0] = fminf(1.0f, ht / logf(64.0f));
    }
    __syncthreads();
    const float gain = sh_fmisc[0];
    int kd = (int)(2048.0f * (0.05f + 0.25f * gain));
    kd = kd < 1 ? 1 : (kd > NN ? NN : kd);
    select_topk(xkeys, kd, n0, tid, sh_keep, sh_hist, sh_wsum, sh_misc);
    if (tid < CH) {
      const float xm = sh_keep[tid] * sh_xt[tid];
      sh_xstate[tid] = xm;
      sh_ffac[tid] = (xm <= 0.0f) ? (1.0f - 0.01f) : 1.0f;
    }
    __syncthreads();
    {
      const float vd = sh_v[par][d4];
      float* rr = &sh_rho[d4][0];
      #pragma unroll
      for (int j = 0; j < 32; ++j) {
        const int c = p4 + 4*j;
        rr[c] = 0.97f * (rr[c]*sh_ffac[c] + gain * (vd * sh_xstate[c]));
      }
    }
    __syncthreads();   // protect sh_v/sh_xstate/rho before next iteration
  }
}

extern "C" void kernel_launch(void* const* d_in, const int* in_sizes, int n_in,
                              void* d_out, int out_size, void* d_ws, size_t ws_size,
                              hipStream_t stream) {
  const int*   tokens = (const int*)d_in[0];
  const float* spike  = (const float*)d_in[1];
  const float* Emat   = (const float*)d_in[2];
  const float* Dx     = (const float*)d_in[3];
  const float* Dy     = (const float*)d_in[4];
  const float* temb   = (const float*)d_in[5];
  float* out = (float*)d_out;
  (void)in_sizes; (void)n_in; (void)out_size; (void)d_ws; (void)ws_size;
  bdh_init<<<dim3(1), dim3(64), 0, stream>>>();
  bdh_main<<<dim3(NB), dim3(NTH), 0, stream>>>(tokens, spike, Emat, Dx, Dy, temb, out);
}